// Round 18
// baseline (671.087 us; speedup 1.0000x reference)
//
#include <hip/hip_runtime.h>
#include <hip/hip_bf16.h>

#define B_SZ 32
#define LSEQ 401
#define NT (B_SZ * LSEQ)        // 12832 tokens (= 802 * 16)
#define DM 192
#define DI 384
#define DS 16
#define EPSF 1e-5f
#define ST 40                   // scan timesteps per LDS tile
#define STP 44                  // padded stride
#define NCH 8                   // scan chunks: [0,51) then 7 x 50
#define PQN 1376256             // 7 * 32 * 12 * 512 boundary states per array

typedef __attribute__((ext_vector_type(8))) short short8;   // 8 bf16 = 4 VGPRs
typedef __attribute__((ext_vector_type(4))) float f32x4;
typedef __hip_bfloat16 bf16;

// ---- f32 mirror element offsets for the 18 inputs ----
#define OFF_IMGS    0
#define OFF_PATCHW  51200
#define OFF_PATCHB  51968
#define OFF_POS     52160
#define OFF_CLS     129152
#define OFF_NORMW   129344
#define OFF_INW     130112
#define OFF_CONVW   719936
#define OFF_CONVB   726080
#define OFF_XPROJW  727616
#define OFF_DTW     795200
#define OFF_DTB     813632
#define OFF_ALOG    815168
#define OFF_DP      839744
#define OFF_OUTW    841280
#define OFF_NORMF   1136192
#define OFF_HEADW   1136384
#define OFF_HEADB   1328384
#define OFF_TOTAL   1329384

// ---- bf16 weight mirror offsets (elements) ----
#define WB_INW   0
#define WB_XPJ   589824            // 4*768*192
#define WB_OUT   688128            // + 4*64*384 (xproj padded 44->64 rows)
#define WB_DTW   983040            // + 4*192*384
#define WB_TOTAL 1032192           // + 4*384*32 (dtw K-padded 12->32)

__device__ __forceinline__ int chunk_s(int c) { return c == 0 ? 0 : c * 50 + 1; }
__device__ __forceinline__ int chunk_e(int c) { return (c + 1) * 50 + 1; }

__device__ __forceinline__ float ldsrc(const void* p, int off, int isbf) {
  return isbf ? __bfloat162float(((const bf16*)p)[off]) : ((const float*)p)[off];
}
__device__ __forceinline__ float fast_silu(float z) {
  return z * __builtin_amdgcn_rcpf(1.f + __expf(-z));
}
__device__ __forceinline__ float fast_softplus(float x) {
  float e = __expf(x);
  return (x > 15.f) ? x : __logf(1.f + e);
}

// ---------------- 16-lane row sum via DPP (VALU pipe) ----------------
#define DPP_ADD(x, ctrl) \
  x += __int_as_float(__builtin_amdgcn_update_dpp(0, __float_as_int(x), ctrl, 0xF, 0xF, true))
__device__ __forceinline__ float row_sum16(float x) {
  DPP_ADD(x, 0xB1);    // quad_perm xor1
  DPP_ADD(x, 0x4E);    // quad_perm xor2
  DPP_ADD(x, 0x124);   // row_ror:4
  DPP_ADD(x, 0x128);   // row_ror:8
  return x;
}

struct P18 { const void* p[18]; };

// ---------------- merged: f32 mirror + bf16 weight mirror (flag inline) ----------------
__global__ __launch_bounds__(256) void k_convwb(P18 t, float* __restrict__ fin,
                                                bf16* __restrict__ wb) {
  static const int st[19] = {OFF_IMGS, OFF_PATCHW, OFF_PATCHB, OFF_POS, OFF_CLS,
                             OFF_NORMW, OFF_INW, OFF_CONVW, OFF_CONVB, OFF_XPROJW,
                             OFF_DTW, OFF_DTB, OFF_ALOG, OFF_DP, OFF_OUTW,
                             OFF_NORMF, OFF_HEADW, OFF_HEADB, OFF_TOTAL};
  int isbf = (((const unsigned short*)t.p[5])[0] == 0x3F80) ? 1 : 0;
  int idx = blockIdx.x * 256 + threadIdx.x;
  if (idx < OFF_TOTAL) {
    int lo = 0;
#pragma unroll
    for (int i = 1; i < 18; ++i) if (idx >= st[i]) lo = i;
    fin[idx] = ldsrc(t.p[lo], idx - st[lo], isbf);
  } else if (idx < OFF_TOTAL + WB_TOTAL) {
    int j = idx - OFF_TOTAL;
    float v;
    if (j < WB_XPJ) {
      v = ldsrc(t.p[6], j, isbf);
    } else if (j < WB_OUT) {
      int i2 = j - WB_XPJ;
      int l = i2 / (64 * 384);
      int r = (i2 / 384) & 63;
      int k = i2 % 384;
      v = (r < 44) ? ldsrc(t.p[9], l * 44 * 384 + r * 384 + k, isbf) : 0.f;
    } else if (j < WB_DTW) {
      v = ldsrc(t.p[14], j - WB_OUT, isbf);
    } else {
      int i2 = j - WB_DTW;
      int l = i2 / (384 * 32);
      int r = i2 % (384 * 32);
      int d = r >> 5;
      int k = r & 31;
      v = (k < 12) ? ldsrc(t.p[10], l * 4608 + d * 12 + k, isbf) : 0.f;
    }
    wb[j] = __float2bfloat16(v);
  }
}

// ---------------- embed + rmsnorm -> residual (f32) + hbufb (bf16) ----------------
__global__ void k_embed(const float* __restrict__ fin, float* __restrict__ residual,
                        bf16* __restrict__ hbufb) {
  const float* imgs = fin + OFF_IMGS;
  const float* pw   = fin + OFF_PATCHW;
  const float* pb   = fin + OFF_PATCHB;
  const float* pos  = fin + OFF_POS;
  const float* cls  = fin + OFF_CLS;
  const float* nw0  = fin + OFF_NORMW;
  int t = blockIdx.x;
  int d = threadIdx.x;           // blockDim = 192
  int b = t / LSEQ;
  int l = t % LSEQ;
  float v;
  if (l < 400) {
    v = pb[d] + pos[l * DM + d];
#pragma unroll
    for (int s = 0; s < 4; ++s)
      v = fmaf(imgs[b * 1600 + l * 4 + s], pw[s * DM + d], v);
  } else {
    v = cls[d] + pos[400 * DM + d];
  }
  residual[(size_t)t * DM + d] = v;
  float ss = v * v;
#pragma unroll
  for (int m = 32; m >= 1; m >>= 1) ss += __shfl_xor(ss, m, 64);
  __shared__ float partial[3];
  __shared__ float sres;
  if ((threadIdx.x & 63) == 0) partial[threadIdx.x >> 6] = ss;
  __syncthreads();
  if (threadIdx.x == 0)
    sres = rsqrtf((partial[0] + partial[1] + partial[2]) / (float)DM + EPSF);
  __syncthreads();
  hbufb[(size_t)t * DM + d] = __float2bfloat16(v * sres * nw0[d]);
}

// ---------------- in_proj: hbufb[NT,192] @ Win[768,192]^T -> xb,zb (coalesced stores) ----------------
// grid (3, NT/16), block 256 (4 waves); block covers cols [cg*256, cg*256+256)
__global__ __launch_bounds__(256) void k_in(const bf16* __restrict__ hbufb,
                                            const bf16* __restrict__ Win,
                                            bf16* __restrict__ xb,
                                            bf16* __restrict__ zb) {
  __shared__ bf16 sOut[16][264];
  int tid = threadIdx.x;
  int lane = tid & 63, wave = tid >> 6;
  int cg = blockIdx.x;
  int row0 = blockIdx.y * 16;
  int q = lane >> 4, mlo = lane & 15;
  const bf16* arow = hbufb + (size_t)(row0 + mlo) * DM + q * 8;
  short8 a[6];
#pragma unroll
  for (int kk = 0; kk < 6; ++kk) a[kk] = *(const short8*)(arow + kk * 32);
  int colbase = cg * 256 + wave * 64;
#pragma unroll
  for (int jt = 0; jt < 4; ++jt) {
    int col = colbase + jt * 16;
    f32x4 acc = {};
#pragma unroll
    for (int kk = 0; kk < 6; ++kk) {
      short8 b = *(const short8*)(Win + (size_t)(col + mlo) * DM + kk * 32 + q * 8);
      acc = __builtin_amdgcn_mfma_f32_16x16x32_bf16(a[kk], b, acc, 0, 0, 0);
    }
#pragma unroll
    for (int i = 0; i < 4; ++i)
      sOut[q * 4 + i][wave * 64 + jt * 16 + mlo] = __float2bfloat16(acc[i]);
  }
  __syncthreads();
  // coalesced store: thread = (row, seg); each thread stores 16 elems (2 x short8)
  int row = tid >> 4, seg = tid & 15;
  size_t t = row0 + row;
  int lcol = seg * 16;
  int gcol = cg * 256 + lcol;
  short8 v0 = *(const short8*)&sOut[row][lcol];
  short8 v1 = *(const short8*)&sOut[row][lcol + 8];
  if (gcol < DI) {
    *(short8*)(xb + t * DI + gcol) = v0;
    *(short8*)(xb + t * DI + gcol + 8) = v1;
  } else {
    int zc = gcol - DI;
    *(short8*)(zb + t * DI + zc) = v0;
    *(short8*)(zb + t * DI + zc + 8) = v1;
  }
}

// ---------------- out_proj + residual + rmsnorm -> residual (f32) + hbufb (bf16) ----------------
// grid NT/16, block 256 (4 waves x 48 cols, full K)
__global__ __launch_bounds__(256) void k_out(const bf16* __restrict__ yb,
                                             const bf16* __restrict__ Wout,
                                             float* __restrict__ residual,
                                             const float* __restrict__ nw,
                                             bf16* __restrict__ hbufb) {
  __shared__ float sCt[16][200];
  int tid = threadIdx.x;
  int lane = tid & 63, wave = tid >> 6;
  int row0 = blockIdx.x * 16;
  int q = lane >> 4, mlo = lane & 15;
  int colw = wave * 48;
  const bf16* arow = yb + (size_t)(row0 + mlo) * DI + q * 8;
  short8 a[12];
#pragma unroll
  for (int kk = 0; kk < 12; ++kk) a[kk] = *(const short8*)(arow + kk * 32);
  f32x4 acc[3] = {};
#pragma unroll
  for (int j = 0; j < 3; ++j) {
    const bf16* brow = Wout + (size_t)(colw + j * 16 + mlo) * DI + q * 8;
#pragma unroll
    for (int kk = 0; kk < 12; ++kk) {
      short8 b = *(const short8*)(brow + kk * 32);
      acc[j] = __builtin_amdgcn_mfma_f32_16x16x32_bf16(a[kk], b, acc[j], 0, 0, 0);
    }
  }
#pragma unroll
  for (int j = 0; j < 3; ++j)
#pragma unroll
    for (int i = 0; i < 4; ++i) sCt[q * 4 + i][colw + j * 16 + mlo] = acc[j][i];
  __syncthreads();
  int row = tid >> 4, g = tid & 15;
  size_t t = row0 + row;
  float rn[12], ss = 0.f;
#pragma unroll
  for (int k = 0; k < 12; ++k) {
    int col = g + 16 * k;
    float x = sCt[row][col] + residual[t * DM + col];
    rn[k] = x;
    ss = fmaf(x, x, ss);
  }
  ss = row_sum16(ss);
  float sres = rsqrtf(ss / (float)DM + EPSF);
#pragma unroll
  for (int k = 0; k < 12; ++k) {
    int col = g + 16 * k;
    residual[t * DM + col] = rn[k];
    hbufb[t * DM + col] = __float2bfloat16(rn[k] * sres * nw[col]);
  }
}

// ---------------- fused: conv+SiLU -> u, x_proj MFMA (K-split), dt via MFMA, 8 waves ----------------
// grid NT/16, block 512
__global__ __launch_bounds__(512) void k_xdt(const bf16* __restrict__ xb,
                                             const float* __restrict__ cw,
                                             const float* __restrict__ cb,
                                             const bf16* __restrict__ Wbf,
                                             float* __restrict__ xdbl,
                                             const bf16* __restrict__ dtwb,
                                             const float* __restrict__ dtb,
                                             bf16* __restrict__ ub,
                                             bf16* __restrict__ dto) {
  __shared__ bf16  sxt[19][392];
  __shared__ bf16  su[16][392];
  __shared__ float4 scw4[384];
  __shared__ float scb[384];
  __shared__ float sxp[2][16][48];   // x_proj partials (2 K-halves)
  __shared__ bf16  sxb[16][32];
  int row0 = blockIdx.x * 16;
  int tid = threadIdx.x;
  for (int i = tid; i < 19 * 48; i += 512) {
    int r = i / 48, c8 = i - r * 48;
    int t = row0 - 3 + r;
    if (t < 0) t = 0;
    *(short8*)&sxt[r][c8 * 8] = *(const short8*)(xb + (size_t)t * DI + c8 * 8);
  }
  for (int i = tid; i < 384; i += 512) {
    scw4[i] = ((const float4*)cw)[i];
    scb[i] = cb[i];
  }
  __syncthreads();
  for (int i = tid; i < 768; i += 512) {
    int tok = i / 48;
    int c8 = i - tok * 48;
    int d0 = c8 * 8;
    int t = row0 + tok;
    int l = t % LSEQ;
    float xr[4][8];
#pragma unroll
    for (int k = 0; k < 4; ++k) {
      short8 v = *(const short8*)&sxt[tok + k][d0];
      bool ok = (l - 3 + k) >= 0;
#pragma unroll
      for (int j = 0; j < 8; ++j) {
        unsigned int uu = ((unsigned int)(unsigned short)v[j]) << 16;
        xr[k][j] = ok ? __uint_as_float(uu) : 0.f;
      }
    }
    short8 uvv;
#pragma unroll
    for (int j = 0; j < 8; ++j) {
      float4 w = scw4[d0 + j];
      float a = scb[d0 + j];
      a = fmaf(xr[0][j], w.x, a);
      a = fmaf(xr[1][j], w.y, a);
      a = fmaf(xr[2][j], w.z, a);
      a = fmaf(xr[3][j], w.w, a);
      bf16 h = __float2bfloat16(fast_silu(a));
      uvv[j] = *reinterpret_cast<short*>(&h);
    }
    *(short8*)&su[tok][d0] = uvv;
    *(short8*)(ub + (size_t)t * DI + d0) = uvv;
  }
  __syncthreads();
  int lane = tid & 63;
  int wave = tid >> 6;
  int q = lane >> 4;
  int mlo = lane & 15;
  // x_proj: waves 0..5 = 3 colgroups x 2 K-halves (cols 0..47, 44 used)
  if (wave < 6) {
    int colw = (wave % 3) * 16;
    int kh = wave / 3;
    f32x4 acc = {};
    for (int k0 = 0; k0 < 192; k0 += 32) {
      short8 a = *(const short8*)&su[mlo][kh * 192 + k0 + q * 8];
      short8 b = *(const short8*)(Wbf + (size_t)(colw + mlo) * DI + kh * 192 + k0 + q * 8);
      acc = __builtin_amdgcn_mfma_f32_16x16x32_bf16(a, b, acc, 0, 0, 0);
    }
#pragma unroll
    for (int i = 0; i < 4; ++i) sxp[kh][q * 4 + i][colw + mlo] = acc[i];
  }
  __syncthreads();
  for (int i = tid; i < 16 * 44; i += 512) {
    int r = i / 44, c = i - r * 44;
    xdbl[(size_t)(row0 + r) * 44 + c] = sxp[0][r][c] + sxp[1][r][c];
  }
  for (int i = tid; i < 512; i += 512) {
    int tok = i >> 5, k = i & 31;
    sxb[tok][k] = __float2bfloat16(k < 12 ? sxp[0][tok][k] + sxp[1][tok][k] : 0.f);
  }
  __syncthreads();
  // dt MFMA: 24 n-tiles over 8 waves = 3 each
  short8 afrag = *(const short8*)&sxb[mlo][q * 8];
#pragma unroll
  for (int jt = 0; jt < 3; ++jt) {
    int d = (wave * 3 + jt) * 16 + mlo;
    short8 bfrag = *(const short8*)(dtwb + (size_t)d * 32 + q * 8);
    f32x4 acc = {};
    acc = __builtin_amdgcn_mfma_f32_16x16x32_bf16(afrag, bfrag, acc, 0, 0, 0);
    float dtbv = dtb[d];
#pragma unroll
    for (int i = 0; i < 4; ++i)
      dto[(size_t)(row0 + q * 4 + i) * DI + d] =
          __float2bfloat16(fast_softplus(acc[i] + dtbv));
  }
}

// ---------------- scan phase A: chunk summaries, 32-d tile ----------------
// grid (12, 32, NCH-1), block 512 = 32 d x 16 n
__global__ __launch_bounds__(512) void k_scanA(const bf16* __restrict__ ub,
                                               const bf16* __restrict__ dtv,
                                               const float* __restrict__ xdbl,
                                               const float* __restrict__ A_log,
                                               float* __restrict__ Pq) {
  __shared__ float sdt[32][STP], sw[32][STP], sB[16][STP];
  int bx = blockIdx.x, b = blockIdx.y, c = blockIdx.z;
  int d0 = bx * 32;
  int tid = threadIdx.x;
  int dloc = tid >> 4, n = tid & 15;
  float A = -__expf(A_log[(d0 + dloc) * DS + n]);
  float S = 0.f, h = 0.f;
  int base = b * LSEQ;
  int lt = tid >> 5, lj = tid & 31;   // 16 timestep-rows x 32 d (64B lines)
  int s = chunk_s(c), e = chunk_e(c);
  for (int t0 = s; t0 < e; t0 += ST) {
    int tc = min(ST, e - t0);
    for (int tt = lt; tt < tc; tt += 16) {
      int g = base + t0 + tt;
      float dv = __bfloat162float(dtv[(size_t)g * DI + d0 + lj]);
      sdt[lj][tt] = dv;
      sw[lj][tt] = dv * __bfloat162float(ub[(size_t)g * DI + d0 + lj]);
      if (lj < 16) sB[lj][tt] = xdbl[(size_t)g * 44 + 12 + lj];
    }
    __syncthreads();
    int l4 = 0;
    for (; l4 + 4 <= tc; l4 += 4) {
      float4 dt4 = *(const float4*)&sdt[dloc][l4];
      float4 w4  = *(const float4*)&sw[dloc][l4];
      float4 B4  = *(const float4*)&sB[n][l4];
      h = fmaf(__expf(dt4.x * A), h, w4.x * B4.x);
      h = fmaf(__expf(dt4.y * A), h, w4.y * B4.y);
      h = fmaf(__expf(dt4.z * A), h, w4.z * B4.z);
      h = fmaf(__expf(dt4.w * A), h, w4.w * B4.w);
      S += dt4.x + dt4.y + dt4.z + dt4.w;
    }
    for (; l4 < tc; ++l4) {
      float dv = sdt[dloc][l4];
      h = fmaf(__expf(dv * A), h, sw[dloc][l4] * sB[n][l4]);
      S += dv;
    }
    __syncthreads();
  }
  int idx = ((c * B_SZ + b) * 12 + bx) * 512 + tid;
  Pq[idx] = __expf(A * S);
  Pq[PQN + idx] = h;
}

// ---------------- scan phase B: full scan per chunk, 32-d tile ----------------
// grid (12, 32, NCH), block 512 = 32 d x 16 n
__global__ __launch_bounds__(512) void k_scanB(const bf16* __restrict__ zb,
                                               const bf16* __restrict__ ub,
                                               const bf16* __restrict__ dtv,
                                               const float* __restrict__ xdbl,
                                               const float* __restrict__ A_log,
                                               const float* __restrict__ Dp,
                                               const float* __restrict__ Pq,
                                               bf16* __restrict__ yb) {
  __shared__ float sdt[32][STP], sw[32][STP], sB[16][STP], sC[16][STP],
                   sz[32][STP], sy[32][STP];    // sy doubles as staged u*D
  int bx = blockIdx.x, b = blockIdx.y, c = blockIdx.z;
  int d0 = bx * 32;
  int tid = threadIdx.x;
  int dloc = tid >> 4, n = tid & 15;
  float A = -__expf(A_log[(d0 + dloc) * DS + n]);
  float h = 0.f;
  for (int j = 0; j < c; ++j) {
    int idx = ((j * B_SZ + b) * 12 + bx) * 512 + tid;
    h = Pq[PQN + idx] + Pq[idx] * h;
  }
  int base = b * LSEQ;
  int lt = tid >> 5, lj = tid & 31;   // 16 timestep-rows x 32 d (64B lines)
  float Dvj = Dp[d0 + lj];
  int s = chunk_s(c), e = chunk_e(c);
  for (int t0 = s; t0 < e; t0 += ST) {
    int tc = min(ST, e - t0);
    for (int tt = lt; tt < tc; tt += 16) {
      int g = base + t0 + tt;
      float dv = __bfloat162float(dtv[(size_t)g * DI + d0 + lj]);
      float uv = __bfloat162float(ub[(size_t)g * DI + d0 + lj]);
      sdt[lj][tt] = dv;
      sw[lj][tt] = dv * uv;
      sy[lj][tt] = uv * Dvj;
      sz[lj][tt] = fast_silu(__bfloat162float(zb[(size_t)g * DI + d0 + lj]));
      if (lj < 32) {
        float v = xdbl[(size_t)g * 44 + 12 + lj];
        if (lj < 16) sB[lj][tt] = v;
        else         sC[lj - 16][tt] = v;
      }
    }
    __syncthreads();
    int l4 = 0;
    for (; l4 + 4 <= tc; l4 += 4) {
      float4 dt4 = *(const float4*)&sdt[dloc][l4];
      float4 w4  = *(const float4*)&sw[dloc][l4];
      float4 B4  = *(const float4*)&sB[n][l4];
      float4 C4  = *(const float4*)&sC[n][l4];
      float c0, c1, c2, c3;
      h = fmaf(__expf(dt4.x * A), h, w4.x * B4.x); c0 = row_sum16(h * C4.x);
      h = fmaf(__expf(dt4.y * A), h, w4.y * B4.y); c1 = row_sum16(h * C4.y);
      h = fmaf(__expf(dt4.z * A), h, w4.z * B4.z); c2 = row_sum16(h * C4.z);
      h = fmaf(__expf(dt4.w * A), h, w4.w * B4.w); c3 = row_sum16(h * C4.w);
      if (n == 0) {
        float4 uD4 = *(const float4*)&sy[dloc][l4];   // read before overwrite (same lane)
        float4 z4  = *(const float4*)&sz[dloc][l4];
        float4 yv;
        yv.x = (c0 + uD4.x) * z4.x;
        yv.y = (c1 + uD4.y) * z4.y;
        yv.z = (c2 + uD4.z) * z4.z;
        yv.w = (c3 + uD4.w) * z4.w;
        *(float4*)&sy[dloc][l4] = yv;
      }
    }
    for (; l4 < tc; ++l4) {
      h = fmaf(__expf(sdt[dloc][l4] * A), h, sw[dloc][l4] * sB[n][l4]);
      float cc = row_sum16(h * sC[n][l4]);
      if (n == 0) sy[dloc][l4] = (cc + sy[dloc][l4]) * sz[dloc][l4];
    }
    __syncthreads();
    for (int tt = lt; tt < tc; tt += 16)
      yb[(size_t)(base + t0 + tt) * DI + d0 + lj] = __float2bfloat16(sy[lj][tt]);
    __syncthreads();
  }
}

// ---------------- layer-3 out_proj for the 32 cls tokens only ----------------
__global__ __launch_bounds__(256) void k_lastout(const bf16* __restrict__ yb,
                                                 const bf16* __restrict__ Wout,
                                                 const float* __restrict__ resIn,
                                                 float* __restrict__ clsbuf) {
  __shared__ float sCt[16][200];
  int tid = threadIdx.x;
  int lane = tid & 63;
  int wave = tid >> 6;
  int b0 = blockIdx.x * 16;
  int q = lane >> 4;
  int mlo = lane & 15;
  int colw = wave * 48;
  f32x4 acc[3] = {};
  const bf16* arow = yb + ((size_t)(b0 + mlo) * LSEQ + 400) * DI + q * 8;
  for (int k0 = 0; k0 < DI; k0 += 32) {
    short8 a = *(const short8*)(arow + k0);
#pragma unroll
    for (int j = 0; j < 3; ++j) {
      short8 b = *(const short8*)(Wout + (size_t)(colw + j * 16 + mlo) * DI + k0 + q * 8);
      acc[j] = __builtin_amdgcn_mfma_f32_16x16x32_bf16(a, b, acc[j], 0, 0, 0);
    }
  }
#pragma unroll
  for (int j = 0; j < 3; ++j)
#pragma unroll
    for (int i = 0; i < 4; ++i) sCt[q * 4 + i][colw + j * 16 + mlo] = acc[j][i];
  __syncthreads();
  int row = tid >> 4, g = tid & 15;
  int bb = b0 + row;
#pragma unroll
  for (int k = 0; k < 12; ++k) {
    int col = g + 16 * k;
    clsbuf[(size_t)bb * DM + col] =
        sCt[row][col] + resIn[((size_t)bb * LSEQ + 400) * DM + col];
  }
}

// ---------------- final: cls-row norm + head; dtype-flagged output ----------------
__global__ __launch_bounds__(256) void k_final(const float* __restrict__ clsbuf,
                                               const float* __restrict__ fin,
                                               const void* __restrict__ nw_raw,
                                               void* __restrict__ out) {
  const float* normf  = fin + OFF_NORMF;
  const float* head_w = fin + OFF_HEADW;
  const float* head_b = fin + OFF_HEADB;
  __shared__ float clsv[DM];
  __shared__ float partial[4];
  __shared__ float sres;
  int b = blockIdx.x;
  float r = 0.f;
  if (threadIdx.x < DM) r = clsbuf[(size_t)b * DM + threadIdx.x];
  float ss = r * r;
#pragma unroll
  for (int m = 32; m >= 1; m >>= 1) ss += __shfl_xor(ss, m, 64);
  if ((threadIdx.x & 63) == 0) partial[threadIdx.x >> 6] = ss;
  __syncthreads();
  if (threadIdx.x == 0)
    sres = rsqrtf((partial[0] + partial[1] + partial[2] + partial[3]) / (float)DM + EPSF);
  __syncthreads();
  if (threadIdx.x < DM) clsv[threadIdx.x] = r * sres * normf[threadIdx.x];
  __syncthreads();
  int isbf = (((const unsigned short*)nw_raw)[0] == 0x3F80) ? 1 : 0;
  for (int e = threadIdx.x; e < 1000; e += 256) {
    float acc = head_b[e];
    for (int k = 0; k < DM; ++k) acc = fmaf(clsv[k], head_w[e * DM + k], acc);
    if (isbf) ((bf16*)out)[b * 1000 + e] = __float2bfloat16(acc);
    else      ((float*)out)[b * 1000 + e] = acc;
  }
}

extern "C" void kernel_launch(void* const* d_in, const int* in_sizes, int n_in,
                              void* d_out, int out_size, void* d_ws, size_t ws_size,
                              hipStream_t stream) {
  char* base = (char*)d_ws;
  size_t off = 0;
  auto alloc = [&](size_t bytes) { char* p = base + off; off = (off + bytes + 255) & ~(size_t)255; return p; };
  float* fin      = (float*)alloc((size_t)OFF_TOTAL * 4);
  bf16*  wb       = (bf16*)alloc((size_t)WB_TOTAL * 2);
  float* residual = (float*)alloc((size_t)NT * DM * 4);
  bf16*  hbufb    = (bf16*)alloc((size_t)NT * DM * 2);
  bf16*  xb       = (bf16*)alloc((size_t)NT * DI * 2);
  bf16*  zb       = (bf16*)alloc((size_t)NT * DI * 2);
  bf16*  ub       = (bf16*)alloc((size_t)NT * DI * 2);
  float* xdbl     = (float*)alloc((size_t)NT * 44 * 4);
  bf16*  dtb16    = (bf16*)alloc((size_t)NT * DI * 2);
  float* Pq       = (float*)alloc((size_t)2 * PQN * 4);
  float* clsbuf   = (float*)alloc((size_t)B_SZ * DM * 4);
  bf16*  yb       = ub;          // in-place y over u (per-tile read-before-write)

  P18 t;
  for (int i = 0; i < 18; ++i) t.p[i] = d_in[i];
  k_convwb<<<(OFF_TOTAL + WB_TOTAL + 255) / 256, 256, 0, stream>>>(t, fin, wb);

  // embed + rmsnorm
  k_embed<<<NT, DM, 0, stream>>>(fin, residual, hbufb);

  for (int layer = 0; layer < 4; ++layer) {
    const float* dtb = fin + OFF_DTB + layer * DI;
    const float* alog = fin + OFF_ALOG + layer * DI * DS;

    // in_proj from hbufb -> xb,zb
    k_in<<<dim3(3, NT / 16), 256, 0, stream>>>(hbufb, wb + WB_INW + layer * 768 * DM,
                                               xb, zb);

    // conv+silu -> u ; x_proj MFMA ; dt via MFMA
    k_xdt<<<NT / 16, 512, 0, stream>>>(xb, fin + OFF_CONVW + layer * DI * 4,
                                       fin + OFF_CONVB + layer * DI,
                                       wb + WB_XPJ + layer * 64 * DI, xdbl,
                                       wb + WB_DTW + layer * 384 * 32, dtb, ub, dtb16);

    k_scanA<<<dim3(12, B_SZ, NCH - 1), 512, 0, stream>>>(ub, dtb16, xdbl, alog, Pq);
    k_scanB<<<dim3(12, B_SZ, NCH), 512, 0, stream>>>(zb, ub, dtb16, xdbl, alog,
                                                     fin + OFF_DP + layer * DI, Pq, yb);

    if (layer < 3) {
      // out_proj + residual + rmsnorm -> hbufb for next layer
      k_out<<<NT / 16, 256, 0, stream>>>(yb, wb + WB_OUT + layer * DM * DI, residual,
                                         fin + OFF_NORMW + (layer + 1) * DM, hbufb);
    } else {
      k_lastout<<<2, 256, 0, stream>>>(yb, wb + WB_OUT + 3 * DM * DI, residual, clsbuf);
    }
  }
  k_final<<<B_SZ, 256, 0, stream>>>(clsbuf, fin, d_in[5], d_out);
}

// Round 19
// 652.404 us; speedup vs baseline: 1.0286x; 1.0286x over previous
//
#include <hip/hip_runtime.h>
#include <hip/hip_bf16.h>

#define B_SZ 32
#define LSEQ 401
#define NT (B_SZ * LSEQ)        // 12832 tokens (= 802 * 16)
#define DM 192
#define DI 384
#define DS 16
#define EPSF 1e-5f
#define ST 40                   // scan timesteps per LDS tile
#define STP 44                  // padded stride
#define NCH 8                   // scan chunks: [0,51) then 7 x 50
#define PQN 1376256             // 7 * 32 * 12 * 512 boundary states per array

typedef __attribute__((ext_vector_type(8))) short short8;   // 8 bf16 = 4 VGPRs
typedef __attribute__((ext_vector_type(4))) float f32x4;
typedef __hip_bfloat16 bf16;

// ---- f32 mirror element offsets for the 18 inputs ----
#define OFF_IMGS    0
#define OFF_PATCHW  51200
#define OFF_PATCHB  51968
#define OFF_POS     52160
#define OFF_CLS     129152
#define OFF_NORMW   129344
#define OFF_INW     130112
#define OFF_CONVW   719936
#define OFF_CONVB   726080
#define OFF_XPROJW  727616
#define OFF_DTW     795200
#define OFF_DTB     813632
#define OFF_ALOG    815168
#define OFF_DP      839744
#define OFF_OUTW    841280
#define OFF_NORMF   1136192
#define OFF_HEADW   1136384
#define OFF_HEADB   1328384
#define OFF_TOTAL   1329384

// ---- bf16 weight mirror offsets (elements) ----
#define WB_INW   0
#define WB_XPJ   589824            // 4*768*192
#define WB_OUT   688128            // + 4*64*384 (xproj padded 44->64 rows)
#define WB_DTW   983040            // + 4*192*384
#define WB_TOTAL 1032192           // + 4*384*32 (dtw K-padded 12->32)

__device__ __forceinline__ int chunk_s(int c) { return c == 0 ? 0 : c * 50 + 1; }
__device__ __forceinline__ int chunk_e(int c) { return (c + 1) * 50 + 1; }

__device__ __forceinline__ float ldsrc(const void* p, int off, int isbf) {
  return isbf ? __bfloat162float(((const bf16*)p)[off]) : ((const float*)p)[off];
}
__device__ __forceinline__ float fast_silu(float z) {
  return z * __builtin_amdgcn_rcpf(1.f + __expf(-z));
}
__device__ __forceinline__ float fast_softplus(float x) {
  float e = __expf(x);
  return (x > 15.f) ? x : __logf(1.f + e);
}

// ---------------- 16-lane row sum via DPP (VALU pipe) ----------------
#define DPP_ADD(x, ctrl) \
  x += __int_as_float(__builtin_amdgcn_update_dpp(0, __float_as_int(x), ctrl, 0xF, 0xF, true))
__device__ __forceinline__ float row_sum16(float x) {
  DPP_ADD(x, 0xB1);    // quad_perm xor1
  DPP_ADD(x, 0x4E);    // quad_perm xor2
  DPP_ADD(x, 0x124);   // row_ror:4
  DPP_ADD(x, 0x128);   // row_ror:8
  return x;
}

struct P18 { const void* p[18]; };

// ---------------- merged: f32 mirror + bf16 weight mirror (flag inline) ----------------
__global__ __launch_bounds__(256) void k_convwb(P18 t, float* __restrict__ fin,
                                                bf16* __restrict__ wb) {
  static const int st[19] = {OFF_IMGS, OFF_PATCHW, OFF_PATCHB, OFF_POS, OFF_CLS,
                             OFF_NORMW, OFF_INW, OFF_CONVW, OFF_CONVB, OFF_XPROJW,
                             OFF_DTW, OFF_DTB, OFF_ALOG, OFF_DP, OFF_OUTW,
                             OFF_NORMF, OFF_HEADW, OFF_HEADB, OFF_TOTAL};
  int isbf = (((const unsigned short*)t.p[5])[0] == 0x3F80) ? 1 : 0;
  int idx = blockIdx.x * 256 + threadIdx.x;
  if (idx < OFF_TOTAL) {
    int lo = 0;
#pragma unroll
    for (int i = 1; i < 18; ++i) if (idx >= st[i]) lo = i;
    fin[idx] = ldsrc(t.p[lo], idx - st[lo], isbf);
  } else if (idx < OFF_TOTAL + WB_TOTAL) {
    int j = idx - OFF_TOTAL;
    float v;
    if (j < WB_XPJ) {
      v = ldsrc(t.p[6], j, isbf);
    } else if (j < WB_OUT) {
      int i2 = j - WB_XPJ;
      int l = i2 / (64 * 384);
      int r = (i2 / 384) & 63;
      int k = i2 % 384;
      v = (r < 44) ? ldsrc(t.p[9], l * 44 * 384 + r * 384 + k, isbf) : 0.f;
    } else if (j < WB_DTW) {
      v = ldsrc(t.p[14], j - WB_OUT, isbf);
    } else {
      int i2 = j - WB_DTW;
      int l = i2 / (384 * 32);
      int r = i2 % (384 * 32);
      int d = r >> 5;
      int k = r & 31;
      v = (k < 12) ? ldsrc(t.p[10], l * 4608 + d * 12 + k, isbf) : 0.f;
    }
    wb[j] = __float2bfloat16(v);
  }
}

// ---------------- fused: embed + rmsnorm (LDS) + in_proj layer0, 8 waves ----------------
// grid NT/16, block 512
__global__ __launch_bounds__(512) void k_embedin(const float* __restrict__ fin,
                                                 float* __restrict__ residual,
                                                 const bf16* __restrict__ Win,
                                                 bf16* __restrict__ xb,
                                                 bf16* __restrict__ zb) {
  __shared__ bf16 shb[16][200];
  const float* imgs = fin + OFF_IMGS;
  const float* pw   = fin + OFF_PATCHW;
  const float* pb   = fin + OFF_PATCHB;
  const float* pos  = fin + OFF_POS;
  const float* cls  = fin + OFF_CLS;
  const float* nw0  = fin + OFF_NORMW;
  int tid = threadIdx.x;
  int row0 = blockIdx.x * 16;
  if (tid < 256) {
    int row = tid >> 4, g = tid & 15;
    int t = row0 + row;
    int b = t / LSEQ, l = t % LSEQ;
    float im[4];
    if (l < 400) {
#pragma unroll
      for (int s = 0; s < 4; ++s) im[s] = imgs[b * 1600 + l * 4 + s];
    }
    float rn[12], ss = 0.f;
#pragma unroll
    for (int k = 0; k < 12; ++k) {
      int col = g + 16 * k;
      float v;
      if (l < 400) {
        v = pb[col] + pos[l * DM + col];
#pragma unroll
        for (int s = 0; s < 4; ++s) v = fmaf(im[s], pw[s * DM + col], v);
      } else {
        v = cls[col] + pos[400 * DM + col];
      }
      residual[(size_t)t * DM + col] = v;
      rn[k] = v;
      ss = fmaf(v, v, ss);
    }
    ss = row_sum16(ss);
    float sres = rsqrtf(ss / (float)DM + EPSF);
#pragma unroll
    for (int k = 0; k < 12; ++k) {
      int col = g + 16 * k;
      shb[row][col] = __float2bfloat16(rn[k] * sres * nw0[col]);
    }
  }
  __syncthreads();
  // in_proj from LDS: 8 waves x 6 col-tiles
  int lane = tid & 63, wave = tid >> 6;
  int q = lane >> 4, mlo = lane & 15;
  short8 afr[6];
#pragma unroll
  for (int kk = 0; kk < 6; ++kk) afr[kk] = *(const short8*)&shb[mlo][kk * 32 + q * 8];
  int t0r = row0 + q * 4;
#pragma unroll
  for (int j = 0; j < 6; ++j) {
    int col = wave * 96 + j * 16;
    f32x4 acc = {};
#pragma unroll
    for (int kk = 0; kk < 6; ++kk) {
      short8 bf = *(const short8*)(Win + (size_t)(col + mlo) * DM + kk * 32 + q * 8);
      acc = __builtin_amdgcn_mfma_f32_16x16x32_bf16(afr[kk], bf, acc, 0, 0, 0);
    }
    int n = col + mlo;
    if (n < DI) {
#pragma unroll
      for (int i = 0; i < 4; ++i)
        xb[(size_t)(t0r + i) * DI + n] = __float2bfloat16(acc[i]);
    } else {
      int nz = n - DI;
#pragma unroll
      for (int i = 0; i < 4; ++i)
        zb[(size_t)(t0r + i) * DI + nz] = __float2bfloat16(acc[i]);
    }
  }
}

// ---------------- fused: conv+SiLU -> u, x_proj MFMA (K-split), dt via MFMA, 8 waves ----------------
// grid NT/16, block 512
__global__ __launch_bounds__(512) void k_xdt(const bf16* __restrict__ xb,
                                             const float* __restrict__ cw,
                                             const float* __restrict__ cb,
                                             const bf16* __restrict__ Wbf,
                                             float* __restrict__ xdbl,
                                             const bf16* __restrict__ dtwb,
                                             const float* __restrict__ dtb,
                                             bf16* __restrict__ ub,
                                             bf16* __restrict__ dto) {
  __shared__ bf16  sxt[19][392];
  __shared__ bf16  su[16][392];
  __shared__ float4 scw4[384];
  __shared__ float scb[384];
  __shared__ float sxp[2][16][48];   // x_proj partials (2 K-halves)
  __shared__ bf16  sxb[16][32];
  int row0 = blockIdx.x * 16;
  int tid = threadIdx.x;
  for (int i = tid; i < 19 * 48; i += 512) {
    int r = i / 48, c8 = i - r * 48;
    int t = row0 - 3 + r;
    if (t < 0) t = 0;
    *(short8*)&sxt[r][c8 * 8] = *(const short8*)(xb + (size_t)t * DI + c8 * 8);
  }
  for (int i = tid; i < 384; i += 512) {
    scw4[i] = ((const float4*)cw)[i];
    scb[i] = cb[i];
  }
  __syncthreads();
  for (int i = tid; i < 768; i += 512) {
    int tok = i / 48;
    int c8 = i - tok * 48;
    int d0 = c8 * 8;
    int t = row0 + tok;
    int l = t % LSEQ;
    float xr[4][8];
#pragma unroll
    for (int k = 0; k < 4; ++k) {
      short8 v = *(const short8*)&sxt[tok + k][d0];
      bool ok = (l - 3 + k) >= 0;
#pragma unroll
      for (int j = 0; j < 8; ++j) {
        unsigned int uu = ((unsigned int)(unsigned short)v[j]) << 16;
        xr[k][j] = ok ? __uint_as_float(uu) : 0.f;
      }
    }
    short8 uvv;
#pragma unroll
    for (int j = 0; j < 8; ++j) {
      float4 w = scw4[d0 + j];
      float a = scb[d0 + j];
      a = fmaf(xr[0][j], w.x, a);
      a = fmaf(xr[1][j], w.y, a);
      a = fmaf(xr[2][j], w.z, a);
      a = fmaf(xr[3][j], w.w, a);
      bf16 h = __float2bfloat16(fast_silu(a));
      uvv[j] = *reinterpret_cast<short*>(&h);
    }
    *(short8*)&su[tok][d0] = uvv;
    *(short8*)(ub + (size_t)t * DI + d0) = uvv;
  }
  __syncthreads();
  int lane = tid & 63;
  int wave = tid >> 6;
  int q = lane >> 4;
  int mlo = lane & 15;
  // x_proj: waves 0..5 = 3 colgroups x 2 K-halves (cols 0..47, 44 used)
  if (wave < 6) {
    int colw = (wave % 3) * 16;
    int kh = wave / 3;
    f32x4 acc = {};
    for (int k0 = 0; k0 < 192; k0 += 32) {
      short8 a = *(const short8*)&su[mlo][kh * 192 + k0 + q * 8];
      short8 b = *(const short8*)(Wbf + (size_t)(colw + mlo) * DI + kh * 192 + k0 + q * 8);
      acc = __builtin_amdgcn_mfma_f32_16x16x32_bf16(a, b, acc, 0, 0, 0);
    }
#pragma unroll
    for (int i = 0; i < 4; ++i) sxp[kh][q * 4 + i][colw + mlo] = acc[i];
  }
  __syncthreads();
  for (int i = tid; i < 16 * 44; i += 512) {
    int r = i / 44, c = i - r * 44;
    xdbl[(size_t)(row0 + r) * 44 + c] = sxp[0][r][c] + sxp[1][r][c];
  }
  for (int i = tid; i < 512; i += 512) {
    int tok = i >> 5, k = i & 31;
    sxb[tok][k] = __float2bfloat16(k < 12 ? sxp[0][tok][k] + sxp[1][tok][k] : 0.f);
  }
  __syncthreads();
  // dt MFMA: 24 n-tiles over 8 waves = 3 each
  short8 afrag = *(const short8*)&sxb[mlo][q * 8];
#pragma unroll
  for (int jt = 0; jt < 3; ++jt) {
    int d = (wave * 3 + jt) * 16 + mlo;
    short8 bfrag = *(const short8*)(dtwb + (size_t)d * 32 + q * 8);
    f32x4 acc = {};
    acc = __builtin_amdgcn_mfma_f32_16x16x32_bf16(afrag, bfrag, acc, 0, 0, 0);
    float dtbv = dtb[d];
#pragma unroll
    for (int i = 0; i < 4; ++i)
      dto[(size_t)(row0 + q * 4 + i) * DI + d] =
          __float2bfloat16(fast_softplus(acc[i] + dtbv));
  }
}

// ---------------- scan phase A: chunk summaries, 32-d tile ----------------
// grid (12, 32, NCH-1), block 512 = 32 d x 16 n
__global__ __launch_bounds__(512) void k_scanA(const bf16* __restrict__ ub,
                                               const bf16* __restrict__ dtv,
                                               const float* __restrict__ xdbl,
                                               const float* __restrict__ A_log,
                                               float* __restrict__ Pq) {
  __shared__ float sdt[32][STP], sw[32][STP], sB[16][STP];
  int bx = blockIdx.x, b = blockIdx.y, c = blockIdx.z;
  int d0 = bx * 32;
  int tid = threadIdx.x;
  int dloc = tid >> 4, n = tid & 15;
  float A = -__expf(A_log[(d0 + dloc) * DS + n]);
  float S = 0.f, h = 0.f;
  int base = b * LSEQ;
  int lt = tid >> 5, lj = tid & 31;   // 16 timestep-rows x 32 d (64B lines)
  int s = chunk_s(c), e = chunk_e(c);
  for (int t0 = s; t0 < e; t0 += ST) {
    int tc = min(ST, e - t0);
    for (int tt = lt; tt < tc; tt += 16) {
      int g = base + t0 + tt;
      float dv = __bfloat162float(dtv[(size_t)g * DI + d0 + lj]);
      sdt[lj][tt] = dv;
      sw[lj][tt] = dv * __bfloat162float(ub[(size_t)g * DI + d0 + lj]);
      if (lj < 16) sB[lj][tt] = xdbl[(size_t)g * 44 + 12 + lj];
    }
    __syncthreads();
    int l4 = 0;
    for (; l4 + 4 <= tc; l4 += 4) {
      float4 dt4 = *(const float4*)&sdt[dloc][l4];
      float4 w4  = *(const float4*)&sw[dloc][l4];
      float4 B4  = *(const float4*)&sB[n][l4];
      h = fmaf(__expf(dt4.x * A), h, w4.x * B4.x);
      h = fmaf(__expf(dt4.y * A), h, w4.y * B4.y);
      h = fmaf(__expf(dt4.z * A), h, w4.z * B4.z);
      h = fmaf(__expf(dt4.w * A), h, w4.w * B4.w);
      S += dt4.x + dt4.y + dt4.z + dt4.w;
    }
    for (; l4 < tc; ++l4) {
      float dv = sdt[dloc][l4];
      h = fmaf(__expf(dv * A), h, sw[dloc][l4] * sB[n][l4]);
      S += dv;
    }
    __syncthreads();
  }
  int idx = ((c * B_SZ + b) * 12 + bx) * 512 + tid;
  Pq[idx] = __expf(A * S);
  Pq[PQN + idx] = h;
}

// ---------------- scan phase B: full scan per chunk, 32-d tile ----------------
// grid (12, 32, NCH), block 512 = 32 d x 16 n
__global__ __launch_bounds__(512) void k_scanB(const bf16* __restrict__ zb,
                                               const bf16* __restrict__ ub,
                                               const bf16* __restrict__ dtv,
                                               const float* __restrict__ xdbl,
                                               const float* __restrict__ A_log,
                                               const float* __restrict__ Dp,
                                               const float* __restrict__ Pq,
                                               bf16* __restrict__ yb) {
  __shared__ float sdt[32][STP], sw[32][STP], sB[16][STP], sC[16][STP],
                   sz[32][STP], sy[32][STP];    // sy doubles as staged u*D
  int bx = blockIdx.x, b = blockIdx.y, c = blockIdx.z;
  int d0 = bx * 32;
  int tid = threadIdx.x;
  int dloc = tid >> 4, n = tid & 15;
  float A = -__expf(A_log[(d0 + dloc) * DS + n]);
  float h = 0.f;
  for (int j = 0; j < c; ++j) {
    int idx = ((j * B_SZ + b) * 12 + bx) * 512 + tid;
    h = Pq[PQN + idx] + Pq[idx] * h;
  }
  int base = b * LSEQ;
  int lt = tid >> 5, lj = tid & 31;   // 16 timestep-rows x 32 d (64B lines)
  float Dvj = Dp[d0 + lj];
  int s = chunk_s(c), e = chunk_e(c);
  for (int t0 = s; t0 < e; t0 += ST) {
    int tc = min(ST, e - t0);
    for (int tt = lt; tt < tc; tt += 16) {
      int g = base + t0 + tt;
      float dv = __bfloat162float(dtv[(size_t)g * DI + d0 + lj]);
      float uv = __bfloat162float(ub[(size_t)g * DI + d0 + lj]);
      sdt[lj][tt] = dv;
      sw[lj][tt] = dv * uv;
      sy[lj][tt] = uv * Dvj;
      sz[lj][tt] = fast_silu(__bfloat162float(zb[(size_t)g * DI + d0 + lj]));
      if (lj < 32) {
        float v = xdbl[(size_t)g * 44 + 12 + lj];
        if (lj < 16) sB[lj][tt] = v;
        else         sC[lj - 16][tt] = v;
      }
    }
    __syncthreads();
    int l4 = 0;
    for (; l4 + 4 <= tc; l4 += 4) {
      float4 dt4 = *(const float4*)&sdt[dloc][l4];
      float4 w4  = *(const float4*)&sw[dloc][l4];
      float4 B4  = *(const float4*)&sB[n][l4];
      float4 C4  = *(const float4*)&sC[n][l4];
      float c0, c1, c2, c3;
      h = fmaf(__expf(dt4.x * A), h, w4.x * B4.x); c0 = row_sum16(h * C4.x);
      h = fmaf(__expf(dt4.y * A), h, w4.y * B4.y); c1 = row_sum16(h * C4.y);
      h = fmaf(__expf(dt4.z * A), h, w4.z * B4.z); c2 = row_sum16(h * C4.z);
      h = fmaf(__expf(dt4.w * A), h, w4.w * B4.w); c3 = row_sum16(h * C4.w);
      if (n == 0) {
        float4 uD4 = *(const float4*)&sy[dloc][l4];   // read before overwrite (same lane)
        float4 z4  = *(const float4*)&sz[dloc][l4];
        float4 yv;
        yv.x = (c0 + uD4.x) * z4.x;
        yv.y = (c1 + uD4.y) * z4.y;
        yv.z = (c2 + uD4.z) * z4.z;
        yv.w = (c3 + uD4.w) * z4.w;
        *(float4*)&sy[dloc][l4] = yv;
      }
    }
    for (; l4 < tc; ++l4) {
      h = fmaf(__expf(sdt[dloc][l4] * A), h, sw[dloc][l4] * sB[n][l4]);
      float cc = row_sum16(h * sC[n][l4]);
      if (n == 0) sy[dloc][l4] = (cc + sy[dloc][l4]) * sz[dloc][l4];
    }
    __syncthreads();
    for (int tt = lt; tt < tc; tt += 16)
      yb[(size_t)(base + t0 + tt) * DI + d0 + lj] = __float2bfloat16(sy[lj][tt]);
    __syncthreads();
  }
}

// ---------------- fused: out_proj (K-split) + residual + rmsnorm + next in_proj, 8 waves ----------------
// grid NT/16, block 512
__global__ __launch_bounds__(512) void k_outin(const bf16* __restrict__ yb,
                                               const bf16* __restrict__ Wout,
                                               float* __restrict__ residual,
                                               const float* __restrict__ nw,
                                               const bf16* __restrict__ Win,
                                               bf16* __restrict__ xb,
                                               bf16* __restrict__ zb) {
  __shared__ float sCt[2][16][200];
  __shared__ bf16  shb[16][200];
  int tid = threadIdx.x;
  int lane = tid & 63;
  int wave = tid >> 6;
  int row0 = blockIdx.x * 16;
  int q = lane >> 4;
  int mlo = lane & 15;
  // --- out_proj MFMA: 4 colgroups x 2 K-halves ---
  {
    int colw = (wave & 3) * 48;
    int kh = wave >> 2;
    f32x4 acc[3] = {};
    const bf16* arow = yb + (size_t)(row0 + mlo) * DI + kh * 192 + q * 8;
    for (int k0 = 0; k0 < 192; k0 += 32) {
      short8 a = *(const short8*)(arow + k0);
#pragma unroll
      for (int j = 0; j < 3; ++j) {
        short8 b = *(const short8*)(Wout + (size_t)(colw + j * 16 + mlo) * DI +
                                    kh * 192 + k0 + q * 8);
        acc[j] = __builtin_amdgcn_mfma_f32_16x16x32_bf16(a, b, acc[j], 0, 0, 0);
      }
    }
#pragma unroll
    for (int j = 0; j < 3; ++j)
#pragma unroll
      for (int i = 0; i < 4; ++i) sCt[kh][q * 4 + i][colw + j * 16 + mlo] = acc[j][i];
  }
  __syncthreads();
  // --- residual + rmsnorm -> shb (in-place residual; block owns its 16 rows) ---
  if (tid < 256) {
    int row = tid >> 4, g = tid & 15;
    int t = row0 + row;
    float rn[12], ss = 0.f;
#pragma unroll
    for (int k = 0; k < 12; ++k) {
      int col = g + 16 * k;
      float x = sCt[0][row][col] + sCt[1][row][col] + residual[(size_t)t * DM + col];
      rn[k] = x;
      ss = fmaf(x, x, ss);
    }
    ss = row_sum16(ss);
    float sres = rsqrtf(ss / (float)DM + EPSF);
#pragma unroll
    for (int k = 0; k < 12; ++k) {
      int col = g + 16 * k;
      residual[(size_t)t * DM + col] = rn[k];
      shb[row][col] = __float2bfloat16(rn[k] * sres * nw[col]);
    }
  }
  __syncthreads();
  // --- next layer in_proj from LDS: 8 waves x 6 col-tiles ---
  short8 afr[6];
#pragma unroll
  for (int kk = 0; kk < 6; ++kk) afr[kk] = *(const short8*)&shb[mlo][kk * 32 + q * 8];
  int t0r = row0 + q * 4;
#pragma unroll
  for (int j = 0; j < 6; ++j) {
    int col = wave * 96 + j * 16;
    f32x4 acc = {};
#pragma unroll
    for (int kk = 0; kk < 6; ++kk) {
      short8 bf = *(const short8*)(Win + (size_t)(col + mlo) * DM + kk * 32 + q * 8);
      acc = __builtin_amdgcn_mfma_f32_16x16x32_bf16(afr[kk], bf, acc, 0, 0, 0);
    }
    int n = col + mlo;
    if (n < DI) {
#pragma unroll
      for (int i = 0; i < 4; ++i)
        xb[(size_t)(t0r + i) * DI + n] = __float2bfloat16(acc[i]);
    } else {
      int nz = n - DI;
#pragma unroll
      for (int i = 0; i < 4; ++i)
        zb[(size_t)(t0r + i) * DI + nz] = __float2bfloat16(acc[i]);
    }
  }
}

// ---------------- layer-3 out_proj for the 32 cls tokens only ----------------
__global__ __launch_bounds__(256) void k_lastout(const bf16* __restrict__ yb,
                                                 const bf16* __restrict__ Wout,
                                                 const float* __restrict__ resIn,
                                                 float* __restrict__ clsbuf) {
  __shared__ float sCt[16][200];
  int tid = threadIdx.x;
  int lane = tid & 63;
  int wave = tid >> 6;
  int b0 = blockIdx.x * 16;
  int q = lane >> 4;
  int mlo = lane & 15;
  int colw = wave * 48;
  f32x4 acc[3] = {};
  const bf16* arow = yb + ((size_t)(b0 + mlo) * LSEQ + 400) * DI + q * 8;
  for (int k0 = 0; k0 < DI; k0 += 32) {
    short8 a = *(const short8*)(arow + k0);
#pragma unroll
    for (int j = 0; j < 3; ++j) {
      short8 b = *(const short8*)(Wout + (size_t)(colw + j * 16 + mlo) * DI + k0 + q * 8);
      acc[j] = __builtin_amdgcn_mfma_f32_16x16x32_bf16(a, b, acc[j], 0, 0, 0);
    }
  }
#pragma unroll
  for (int j = 0; j < 3; ++j)
#pragma unroll
    for (int i = 0; i < 4; ++i) sCt[q * 4 + i][colw + j * 16 + mlo] = acc[j][i];
  __syncthreads();
  int row = tid >> 4, g = tid & 15;
  int bb = b0 + row;
#pragma unroll
  for (int k = 0; k < 12; ++k) {
    int col = g + 16 * k;
    clsbuf[(size_t)bb * DM + col] =
        sCt[row][col] + resIn[((size_t)bb * LSEQ + 400) * DM + col];
  }
}

// ---------------- final: cls-row norm + head; dtype-flagged output ----------------
__global__ __launch_bounds__(256) void k_final(const float* __restrict__ clsbuf,
                                               const float* __restrict__ fin,
                                               const void* __restrict__ nw_raw,
                                               void* __restrict__ out) {
  const float* normf  = fin + OFF_NORMF;
  const float* head_w = fin + OFF_HEADW;
  const float* head_b = fin + OFF_HEADB;
  __shared__ float clsv[DM];
  __shared__ float partial[4];
  __shared__ float sres;
  int b = blockIdx.x;
  float r = 0.f;
  if (threadIdx.x < DM) r = clsbuf[(size_t)b * DM + threadIdx.x];
  float ss = r * r;
#pragma unroll
  for (int m = 32; m >= 1; m >>= 1) ss += __shfl_xor(ss, m, 64);
  if ((threadIdx.x & 63) == 0) partial[threadIdx.x >> 6] = ss;
  __syncthreads();
  if (threadIdx.x == 0)
    sres = rsqrtf((partial[0] + partial[1] + partial[2] + partial[3]) / (float)DM + EPSF);
  __syncthreads();
  if (threadIdx.x < DM) clsv[threadIdx.x] = r * sres * normf[threadIdx.x];
  __syncthreads();
  int isbf = (((const unsigned short*)nw_raw)[0] == 0x3F80) ? 1 : 0;
  for (int e = threadIdx.x; e < 1000; e += 256) {
    float acc = head_b[e];
    for (int k = 0; k < DM; ++k) acc = fmaf(clsv[k], head_w[e * DM + k], acc);
    if (isbf) ((bf16*)out)[b * 1000 + e] = __float2bfloat16(acc);
    else      ((float*)out)[b * 1000 + e] = acc;
  }
}

extern "C" void kernel_launch(void* const* d_in, const int* in_sizes, int n_in,
                              void* d_out, int out_size, void* d_ws, size_t ws_size,
                              hipStream_t stream) {
  char* base = (char*)d_ws;
  size_t off = 0;
  auto alloc = [&](size_t bytes) { char* p = base + off; off = (off + bytes + 255) & ~(size_t)255; return p; };
  float* fin      = (float*)alloc((size_t)OFF_TOTAL * 4);
  bf16*  wb       = (bf16*)alloc((size_t)WB_TOTAL * 2);
  float* residual = (float*)alloc((size_t)NT * DM * 4);
  bf16*  xb       = (bf16*)alloc((size_t)NT * DI * 2);
  bf16*  zb       = (bf16*)alloc((size_t)NT * DI * 2);
  bf16*  ub       = (bf16*)alloc((size_t)NT * DI * 2);
  float* xdbl     = (float*)alloc((size_t)NT * 44 * 4);
  bf16*  dtb16    = (bf16*)alloc((size_t)NT * DI * 2);
  float* Pq       = (float*)alloc((size_t)2 * PQN * 4);
  float* clsbuf   = (float*)alloc((size_t)B_SZ * DM * 4);
  bf16*  yb       = ub;          // in-place y over u (per-tile read-before-write)

  P18 t;
  for (int i = 0; i < 18; ++i) t.p[i] = d_in[i];
  k_convwb<<<(OFF_TOTAL + WB_TOTAL + 255) / 256, 256, 0, stream>>>(t, fin, wb);

  // embed + rmsnorm + in_proj layer 0
  k_embedin<<<NT / 16, 512, 0, stream>>>(fin, residual, wb + WB_INW, xb, zb);

  for (int layer = 0; layer < 4; ++layer) {
    const float* dtb = fin + OFF_DTB + layer * DI;
    const float* alog = fin + OFF_ALOG + layer * DI * DS;

    // conv+silu -> u ; x_proj MFMA ; dt via MFMA
    k_xdt<<<NT / 16, 512, 0, stream>>>(xb, fin + OFF_CONVW + layer * DI * 4,
                                       fin + OFF_CONVB + layer * DI,
                                       wb + WB_XPJ + layer * 64 * DI, xdbl,
                                       wb + WB_DTW + layer * 384 * 32, dtb, ub, dtb16);

    k_scanA<<<dim3(12, B_SZ, NCH - 1), 512, 0, stream>>>(ub, dtb16, xdbl, alog, Pq);
    k_scanB<<<dim3(12, B_SZ, NCH), 512, 0, stream>>>(zb, ub, dtb16, xdbl, alog,
                                                     fin + OFF_DP + layer * DI, Pq, yb);

    if (layer < 3) {
      k_outin<<<NT / 16, 512, 0, stream>>>(yb, wb + WB_OUT + layer * DM * DI, residual,
                                           fin + OFF_NORMW + (layer + 1) * DM,
                                           wb + WB_INW + (layer + 1) * 768 * DM, xb, zb);
    } else {
      k_lastout<<<2, 256, 0, stream>>>(yb, wb + WB_OUT + 3 * DM * DI, residual, clsbuf);
    }
  }
  k_final<<<B_SZ, 256, 0, stream>>>(clsbuf, fin, d_in[5], d_out);
}

// Round 21
// 650.557 us; speedup vs baseline: 1.0316x; 1.0028x over previous
//
#include <hip/hip_runtime.h>
#include <hip/hip_bf16.h>

#define B_SZ 32
#define LSEQ 401
#define NT (B_SZ * LSEQ)        // 12832 tokens (= 802 * 16)
#define DM 192
#define DI 384
#define DS 16
#define EPSF 1e-5f
#define ST 40                   // scan timesteps per LDS tile
#define STP 44                  // padded stride
#define NCH 8                   // scan chunks: [0,51) then 7 x 50
#define PQN 1376256             // 7 * 32 * 12 * 512 boundary states per array

typedef __attribute__((ext_vector_type(8))) short short8;   // 8 bf16 = 4 VGPRs
typedef __attribute__((ext_vector_type(4))) float f32x4;
typedef __hip_bfloat16 bf16;

// ---- f32 mirror element offsets for the 18 inputs ----
#define OFF_IMGS    0
#define OFF_PATCHW  51200
#define OFF_PATCHB  51968
#define OFF_POS     52160
#define OFF_CLS     129152
#define OFF_NORMW   129344
#define OFF_INW     130112
#define OFF_CONVW   719936
#define OFF_CONVB   726080
#define OFF_XPROJW  727616
#define OFF_DTW     795200
#define OFF_DTB     813632
#define OFF_ALOG    815168
#define OFF_DP      839744
#define OFF_OUTW    841280
#define OFF_NORMF   1136192
#define OFF_HEADW   1136384
#define OFF_HEADB   1328384
#define OFF_TOTAL   1329384

// ---- bf16 weight mirror offsets (elements) ----
#define WB_INW   0
#define WB_XPJ   589824            // 4*768*192
#define WB_OUT   688128            // + 4*64*384 (xproj padded 44->64 rows)
#define WB_DTW   983040            // + 4*192*384
#define WB_TOTAL 1032192           // + 4*384*32 (dtw K-padded 12->32)

__device__ __forceinline__ int chunk_s(int c) { return c == 0 ? 0 : c * 50 + 1; }
__device__ __forceinline__ int chunk_e(int c) { return (c + 1) * 50 + 1; }

__device__ __forceinline__ float ldsrc(const void* p, int off, int isbf) {
  return isbf ? __bfloat162float(((const bf16*)p)[off]) : ((const float*)p)[off];
}
__device__ __forceinline__ float fast_silu(float z) {
  return z * __builtin_amdgcn_rcpf(1.f + __expf(-z));
}
__device__ __forceinline__ float fast_softplus(float x) {
  float e = __expf(x);
  return (x > 15.f) ? x : __logf(1.f + e);
}

// ---------------- 16-lane row sum via DPP (VALU pipe) ----------------
#define DPP_ADD(x, ctrl) \
  x += __int_as_float(__builtin_amdgcn_update_dpp(0, __float_as_int(x), ctrl, 0xF, 0xF, true))
__device__ __forceinline__ float row_sum16(float x) {
  DPP_ADD(x, 0xB1);    // quad_perm xor1
  DPP_ADD(x, 0x4E);    // quad_perm xor2
  DPP_ADD(x, 0x124);   // row_ror:4
  DPP_ADD(x, 0x128);   // row_ror:8
  return x;
}

struct P18 { const void* p[18]; };

// ---------------- merged: f32 mirror + bf16 weight mirror (flag inline) ----------------
__global__ __launch_bounds__(256) void k_convwb(P18 t, float* __restrict__ fin,
                                                bf16* __restrict__ wb) {
  static const int st[19] = {OFF_IMGS, OFF_PATCHW, OFF_PATCHB, OFF_POS, OFF_CLS,
                             OFF_NORMW, OFF_INW, OFF_CONVW, OFF_CONVB, OFF_XPROJW,
                             OFF_DTW, OFF_DTB, OFF_ALOG, OFF_DP, OFF_OUTW,
                             OFF_NORMF, OFF_HEADW, OFF_HEADB, OFF_TOTAL};
  int isbf = (((const unsigned short*)t.p[5])[0] == 0x3F80) ? 1 : 0;
  int idx = blockIdx.x * 256 + threadIdx.x;
  if (idx < OFF_TOTAL) {
    int lo = 0;
#pragma unroll
    for (int i = 1; i < 18; ++i) if (idx >= st[i]) lo = i;
    fin[idx] = ldsrc(t.p[lo], idx - st[lo], isbf);
  } else if (idx < OFF_TOTAL + WB_TOTAL) {
    int j = idx - OFF_TOTAL;
    float v;
    if (j < WB_XPJ) {
      v = ldsrc(t.p[6], j, isbf);
    } else if (j < WB_OUT) {
      int i2 = j - WB_XPJ;
      int l = i2 / (64 * 384);
      int r = (i2 / 384) & 63;
      int k = i2 % 384;
      v = (r < 44) ? ldsrc(t.p[9], l * 44 * 384 + r * 384 + k, isbf) : 0.f;
    } else if (j < WB_DTW) {
      v = ldsrc(t.p[14], j - WB_OUT, isbf);
    } else {
      int i2 = j - WB_DTW;
      int l = i2 / (384 * 32);
      int r = i2 % (384 * 32);
      int d = r >> 5;
      int k = r & 31;
      v = (k < 12) ? ldsrc(t.p[10], l * 4608 + d * 12 + k, isbf) : 0.f;
    }
    wb[j] = __float2bfloat16(v);
  }
}

// ---------------- fused: embed + rmsnorm (LDS) + in_proj layer0, 8 waves ----------------
// grid NT/16, block 512
__global__ __launch_bounds__(512) void k_embedin(const float* __restrict__ fin,
                                                 float* __restrict__ residual,
                                                 const bf16* __restrict__ Win,
                                                 bf16* __restrict__ xb,
                                                 bf16* __restrict__ zb) {
  __shared__ bf16 shb[16][200];
  const float* imgs = fin + OFF_IMGS;
  const float* pw   = fin + OFF_PATCHW;
  const float* pb   = fin + OFF_PATCHB;
  const float* pos  = fin + OFF_POS;
  const float* cls  = fin + OFF_CLS;
  const float* nw0  = fin + OFF_NORMW;
  int tid = threadIdx.x;
  int row0 = blockIdx.x * 16;
  if (tid < 256) {
    int row = tid >> 4, g = tid & 15;
    int t = row0 + row;
    int b = t / LSEQ, l = t % LSEQ;
    float im[4];
    if (l < 400) {
#pragma unroll
      for (int s = 0; s < 4; ++s) im[s] = imgs[b * 1600 + l * 4 + s];
    }
    float rn[12], ss = 0.f;
#pragma unroll
    for (int k = 0; k < 12; ++k) {
      int col = g + 16 * k;
      float v;
      if (l < 400) {
        v = pb[col] + pos[l * DM + col];
#pragma unroll
        for (int s = 0; s < 4; ++s) v = fmaf(im[s], pw[s * DM + col], v);
      } else {
        v = cls[col] + pos[400 * DM + col];
      }
      residual[(size_t)t * DM + col] = v;
      rn[k] = v;
      ss = fmaf(v, v, ss);
    }
    ss = row_sum16(ss);
    float sres = rsqrtf(ss / (float)DM + EPSF);
#pragma unroll
    for (int k = 0; k < 12; ++k) {
      int col = g + 16 * k;
      shb[row][col] = __float2bfloat16(rn[k] * sres * nw0[col]);
    }
  }
  __syncthreads();
  // in_proj from LDS: 8 waves x 6 col-tiles
  int lane = tid & 63, wave = tid >> 6;
  int q = lane >> 4, mlo = lane & 15;
  short8 afr[6];
#pragma unroll
  for (int kk = 0; kk < 6; ++kk) afr[kk] = *(const short8*)&shb[mlo][kk * 32 + q * 8];
  int t0r = row0 + q * 4;
#pragma unroll
  for (int j = 0; j < 6; ++j) {
    int col = wave * 96 + j * 16;
    f32x4 acc = {};
#pragma unroll
    for (int kk = 0; kk < 6; ++kk) {
      short8 bf = *(const short8*)(Win + (size_t)(col + mlo) * DM + kk * 32 + q * 8);
      acc = __builtin_amdgcn_mfma_f32_16x16x32_bf16(afr[kk], bf, acc, 0, 0, 0);
    }
    int n = col + mlo;
    if (n < DI) {
#pragma unroll
      for (int i = 0; i < 4; ++i)
        xb[(size_t)(t0r + i) * DI + n] = __float2bfloat16(acc[i]);
    } else {
      int nz = n - DI;
#pragma unroll
      for (int i = 0; i < 4; ++i)
        zb[(size_t)(t0r + i) * DI + nz] = __float2bfloat16(acc[i]);
    }
  }
}

// ---------------- fused: conv+SiLU -> u, x_proj MFMA (K-split), dt via MFMA, 8 waves ----------------
// grid NT/16, block 512
__global__ __launch_bounds__(512) void k_xdt(const bf16* __restrict__ xb,
                                             const float* __restrict__ cw,
                                             const float* __restrict__ cb,
                                             const bf16* __restrict__ Wbf,
                                             float* __restrict__ xdbl,
                                             const bf16* __restrict__ dtwb,
                                             const float* __restrict__ dtb,
                                             bf16* __restrict__ ub,
                                             bf16* __restrict__ dto) {
  __shared__ bf16  sxt[19][392];
  __shared__ bf16  su[16][392];
  __shared__ float4 scw4[384];
  __shared__ float scb[384];
  __shared__ float sxp[2][16][48];   // x_proj partials (2 K-halves)
  __shared__ bf16  sxb[16][32];
  int row0 = blockIdx.x * 16;
  int tid = threadIdx.x;
  for (int i = tid; i < 19 * 48; i += 512) {
    int r = i / 48, c8 = i - r * 48;
    int t = row0 - 3 + r;
    if (t < 0) t = 0;
    *(short8*)&sxt[r][c8 * 8] = *(const short8*)(xb + (size_t)t * DI + c8 * 8);
  }
  for (int i = tid; i < 384; i += 512) {
    scw4[i] = ((const float4*)cw)[i];
    scb[i] = cb[i];
  }
  __syncthreads();
  for (int i = tid; i < 768; i += 512) {
    int tok = i / 48;
    int c8 = i - tok * 48;
    int d0 = c8 * 8;
    int t = row0 + tok;
    int l = t % LSEQ;
    float xr[4][8];
#pragma unroll
    for (int k = 0; k < 4; ++k) {
      short8 v = *(const short8*)&sxt[tok + k][d0];
      bool ok = (l - 3 + k) >= 0;
#pragma unroll
      for (int j = 0; j < 8; ++j) {
        unsigned int uu = ((unsigned int)(unsigned short)v[j]) << 16;
        xr[k][j] = ok ? __uint_as_float(uu) : 0.f;
      }
    }
    short8 uvv;
#pragma unroll
    for (int j = 0; j < 8; ++j) {
      float4 w = scw4[d0 + j];
      float a = scb[d0 + j];
      a = fmaf(xr[0][j], w.x, a);
      a = fmaf(xr[1][j], w.y, a);
      a = fmaf(xr[2][j], w.z, a);
      a = fmaf(xr[3][j], w.w, a);
      bf16 h = __float2bfloat16(fast_silu(a));
      uvv[j] = *reinterpret_cast<short*>(&h);
    }
    *(short8*)&su[tok][d0] = uvv;
    *(short8*)(ub + (size_t)t * DI + d0) = uvv;
  }
  __syncthreads();
  int lane = tid & 63;
  int wave = tid >> 6;
  int q = lane >> 4;
  int mlo = lane & 15;
  // x_proj: waves 0..5 = 3 colgroups x 2 K-halves (cols 0..47, 44 used)
  if (wave < 6) {
    int colw = (wave % 3) * 16;
    int kh = wave / 3;
    f32x4 acc = {};
    for (int k0 = 0; k0 < 192; k0 += 32) {
      short8 a = *(const short8*)&su[mlo][kh * 192 + k0 + q * 8];
      short8 b = *(const short8*)(Wbf + (size_t)(colw + mlo) * DI + kh * 192 + k0 + q * 8);
      acc = __builtin_amdgcn_mfma_f32_16x16x32_bf16(a, b, acc, 0, 0, 0);
    }
#pragma unroll
    for (int i = 0; i < 4; ++i) sxp[kh][q * 4 + i][colw + mlo] = acc[i];
  }
  __syncthreads();
  for (int i = tid; i < 16 * 44; i += 512) {
    int r = i / 44, c = i - r * 44;
    xdbl[(size_t)(row0 + r) * 44 + c] = sxp[0][r][c] + sxp[1][r][c];
  }
  for (int i = tid; i < 512; i += 512) {
    int tok = i >> 5, k = i & 31;
    sxb[tok][k] = __float2bfloat16(k < 12 ? sxp[0][tok][k] + sxp[1][tok][k] : 0.f);
  }
  __syncthreads();
  // dt MFMA: 24 n-tiles over 8 waves = 3 each
  short8 afrag = *(const short8*)&sxb[mlo][q * 8];
#pragma unroll
  for (int jt = 0; jt < 3; ++jt) {
    int d = (wave * 3 + jt) * 16 + mlo;
    short8 bfrag = *(const short8*)(dtwb + (size_t)d * 32 + q * 8);
    f32x4 acc = {};
    acc = __builtin_amdgcn_mfma_f32_16x16x32_bf16(afrag, bfrag, acc, 0, 0, 0);
    float dtbv = dtb[d];
#pragma unroll
    for (int i = 0; i < 4; ++i)
      dto[(size_t)(row0 + q * 4 + i) * DI + d] =
          __float2bfloat16(fast_softplus(acc[i] + dtbv));
  }
}

// ---------------- scan phase A: chunk summaries, 32-d tile ----------------
// grid (12, 32, NCH-1), block 512 = 32 d x 16 n
__global__ __launch_bounds__(512) void k_scanA(const bf16* __restrict__ ub,
                                               const bf16* __restrict__ dtv,
                                               const float* __restrict__ xdbl,
                                               const float* __restrict__ A_log,
                                               float* __restrict__ Pq) {
  __shared__ float sdt[32][STP], sw[32][STP], sB[16][STP];
  int bx = blockIdx.x, b = blockIdx.y, c = blockIdx.z;
  int d0 = bx * 32;
  int tid = threadIdx.x;
  int dloc = tid >> 4, n = tid & 15;
  float A = -__expf(A_log[(d0 + dloc) * DS + n]);
  float S = 0.f, h = 0.f;
  int base = b * LSEQ;
  int lt = tid >> 5, lj = tid & 31;   // 16 timestep-rows x 32 d (64B lines)
  int s = chunk_s(c), e = chunk_e(c);
  for (int t0 = s; t0 < e; t0 += ST) {
    int tc = min(ST, e - t0);
    for (int tt = lt; tt < tc; tt += 16) {
      int g = base + t0 + tt;
      float dv = __bfloat162float(dtv[(size_t)g * DI + d0 + lj]);
      sdt[lj][tt] = dv;
      sw[lj][tt] = dv * __bfloat162float(ub[(size_t)g * DI + d0 + lj]);
      if (lj < 16) sB[lj][tt] = xdbl[(size_t)g * 44 + 12 + lj];
    }
    __syncthreads();
    int l4 = 0;
    for (; l4 + 4 <= tc; l4 += 4) {
      float4 dt4 = *(const float4*)&sdt[dloc][l4];
      float4 w4  = *(const float4*)&sw[dloc][l4];
      float4 B4  = *(const float4*)&sB[n][l4];
      h = fmaf(__expf(dt4.x * A), h, w4.x * B4.x);
      h = fmaf(__expf(dt4.y * A), h, w4.y * B4.y);
      h = fmaf(__expf(dt4.z * A), h, w4.z * B4.z);
      h = fmaf(__expf(dt4.w * A), h, w4.w * B4.w);
      S += dt4.x + dt4.y + dt4.z + dt4.w;
    }
    for (; l4 < tc; ++l4) {
      float dv = sdt[dloc][l4];
      h = fmaf(__expf(dv * A), h, sw[dloc][l4] * sB[n][l4]);
      S += dv;
    }
    __syncthreads();
  }
  int idx = ((c * B_SZ + b) * 12 + bx) * 512 + tid;
  Pq[idx] = __expf(A * S);
  Pq[PQN + idx] = h;
}

// ---------------- scan phase B: full scan per chunk, 32-d tile ----------------
// grid (12, 32, NCH), block 512 = 32 d x 16 n
__global__ __launch_bounds__(512) void k_scanB(const bf16* __restrict__ zb,
                                               const bf16* __restrict__ ub,
                                               const bf16* __restrict__ dtv,
                                               const float* __restrict__ xdbl,
                                               const float* __restrict__ A_log,
                                               const float* __restrict__ Dp,
                                               const float* __restrict__ Pq,
                                               bf16* __restrict__ yb) {
  __shared__ float sdt[32][STP], sw[32][STP], sB[16][STP], sC[16][STP],
                   sz[32][STP], sy[32][STP];    // sy doubles as staged u*D
  int bx = blockIdx.x, b = blockIdx.y, c = blockIdx.z;
  int d0 = bx * 32;
  int tid = threadIdx.x;
  int dloc = tid >> 4, n = tid & 15;
  float A = -__expf(A_log[(d0 + dloc) * DS + n]);
  float h = 0.f;
  for (int j = 0; j < c; ++j) {
    int idx = ((j * B_SZ + b) * 12 + bx) * 512 + tid;
    h = Pq[PQN + idx] + Pq[idx] * h;
  }
  int base = b * LSEQ;
  int lt = tid >> 5, lj = tid & 31;   // 16 timestep-rows x 32 d (64B lines)
  float Dvj = Dp[d0 + lj];
  int s = chunk_s(c), e = chunk_e(c);
  for (int t0 = s; t0 < e; t0 += ST) {
    int tc = min(ST, e - t0);
    for (int tt = lt; tt < tc; tt += 16) {
      int g = base + t0 + tt;
      float dv = __bfloat162float(dtv[(size_t)g * DI + d0 + lj]);
      float uv = __bfloat162float(ub[(size_t)g * DI + d0 + lj]);
      sdt[lj][tt] = dv;
      sw[lj][tt] = dv * uv;
      sy[lj][tt] = uv * Dvj;
      sz[lj][tt] = fast_silu(__bfloat162float(zb[(size_t)g * DI + d0 + lj]));
      if (lj < 32) {
        float v = xdbl[(size_t)g * 44 + 12 + lj];
        if (lj < 16) sB[lj][tt] = v;
        else         sC[lj - 16][tt] = v;
      }
    }
    __syncthreads();
    int l4 = 0;
    for (; l4 + 4 <= tc; l4 += 4) {
      float4 dt4 = *(const float4*)&sdt[dloc][l4];
      float4 w4  = *(const float4*)&sw[dloc][l4];
      float4 B4  = *(const float4*)&sB[n][l4];
      float4 C4  = *(const float4*)&sC[n][l4];
      float c0, c1, c2, c3;
      h = fmaf(__expf(dt4.x * A), h, w4.x * B4.x); c0 = row_sum16(h * C4.x);
      h = fmaf(__expf(dt4.y * A), h, w4.y * B4.y); c1 = row_sum16(h * C4.y);
      h = fmaf(__expf(dt4.z * A), h, w4.z * B4.z); c2 = row_sum16(h * C4.z);
      h = fmaf(__expf(dt4.w * A), h, w4.w * B4.w); c3 = row_sum16(h * C4.w);
      if (n == 0) {
        float4 uD4 = *(const float4*)&sy[dloc][l4];   // read before overwrite (same lane)
        float4 z4  = *(const float4*)&sz[dloc][l4];
        float4 yv;
        yv.x = (c0 + uD4.x) * z4.x;
        yv.y = (c1 + uD4.y) * z4.y;
        yv.z = (c2 + uD4.z) * z4.z;
        yv.w = (c3 + uD4.w) * z4.w;
        *(float4*)&sy[dloc][l4] = yv;
      }
    }
    for (; l4 < tc; ++l4) {
      h = fmaf(__expf(sdt[dloc][l4] * A), h, sw[dloc][l4] * sB[n][l4]);
      float cc = row_sum16(h * sC[n][l4]);
      if (n == 0) sy[dloc][l4] = (cc + sy[dloc][l4]) * sz[dloc][l4];
    }
    __syncthreads();
    for (int tt = lt; tt < tc; tt += 16)
      yb[(size_t)(base + t0 + tt) * DI + d0 + lj] = __float2bfloat16(sy[lj][tt]);
    __syncthreads();
  }
}

// ---------------- fused: out_proj (K-split) + residual + rmsnorm + next in_proj, 8 waves ----------------
// grid NT/16, block 512
__global__ __launch_bounds__(512) void k_outin(const bf16* __restrict__ yb,
                                               const bf16* __restrict__ Wout,
                                               float* __restrict__ residual,
                                               const float* __restrict__ nw,
                                               const bf16* __restrict__ Win,
                                               bf16* __restrict__ xb,
                                               bf16* __restrict__ zb) {
  __shared__ float sCt[2][16][200];
  __shared__ bf16  shb[16][200];
  int tid = threadIdx.x;
  int lane = tid & 63;
  int wave = tid >> 6;
  int row0 = blockIdx.x * 16;
  int q = lane >> 4;
  int mlo = lane & 15;
  // --- out_proj MFMA: 4 colgroups x 2 K-halves ---
  {
    int colw = (wave & 3) * 48;
    int kh = wave >> 2;
    f32x4 acc[3] = {};
    const bf16* arow = yb + (size_t)(row0 + mlo) * DI + kh * 192 + q * 8;
    for (int k0 = 0; k0 < 192; k0 += 32) {
      short8 a = *(const short8*)(arow + k0);
#pragma unroll
      for (int j = 0; j < 3; ++j) {
        short8 b = *(const short8*)(Wout + (size_t)(colw + j * 16 + mlo) * DI +
                                    kh * 192 + k0 + q * 8);
        acc[j] = __builtin_amdgcn_mfma_f32_16x16x32_bf16(a, b, acc[j], 0, 0, 0);
      }
    }
#pragma unroll
    for (int j = 0; j < 3; ++j)
#pragma unroll
      for (int i = 0; i < 4; ++i) sCt[kh][q * 4 + i][colw + j * 16 + mlo] = acc[j][i];
  }
  __syncthreads();
  // --- residual + rmsnorm -> shb (in-place residual; block owns its 16 rows) ---
  if (tid < 256) {
    int row = tid >> 4, g = tid & 15;
    int t = row0 + row;
    float rn[12], ss = 0.f;
#pragma unroll
    for (int k = 0; k < 12; ++k) {
      int col = g + 16 * k;
      float x = sCt[0][row][col] + sCt[1][row][col] + residual[(size_t)t * DM + col];
      rn[k] = x;
      ss = fmaf(x, x, ss);
    }
    ss = row_sum16(ss);
    float sres = rsqrtf(ss / (float)DM + EPSF);
#pragma unroll
    for (int k = 0; k < 12; ++k) {
      int col = g + 16 * k;
      residual[(size_t)t * DM + col] = rn[k];
      shb[row][col] = __float2bfloat16(rn[k] * sres * nw[col]);
    }
  }
  __syncthreads();
  // --- next layer in_proj from LDS: 8 waves x 6 col-tiles ---
  short8 afr[6];
#pragma unroll
  for (int kk = 0; kk < 6; ++kk) afr[kk] = *(const short8*)&shb[mlo][kk * 32 + q * 8];
  int t0r = row0 + q * 4;
#pragma unroll
  for (int j = 0; j < 6; ++j) {
    int col = wave * 96 + j * 16;
    f32x4 acc = {};
#pragma unroll
    for (int kk = 0; kk < 6; ++kk) {
      short8 bf = *(const short8*)(Win + (size_t)(col + mlo) * DM + kk * 32 + q * 8);
      acc = __builtin_amdgcn_mfma_f32_16x16x32_bf16(afr[kk], bf, acc, 0, 0, 0);
    }
    int n = col + mlo;
    if (n < DI) {
#pragma unroll
      for (int i = 0; i < 4; ++i)
        xb[(size_t)(t0r + i) * DI + n] = __float2bfloat16(acc[i]);
    } else {
      int nz = n - DI;
#pragma unroll
      for (int i = 0; i < 4; ++i)
        zb[(size_t)(t0r + i) * DI + nz] = __float2bfloat16(acc[i]);
    }
  }
}

// ---------------- layer-3 out_proj for the 32 cls tokens only ----------------
__global__ __launch_bounds__(256) void k_lastout(const bf16* __restrict__ yb,
                                                 const bf16* __restrict__ Wout,
                                                 const float* __restrict__ resIn,
                                                 float* __restrict__ clsbuf) {
  __shared__ float sCt[16][200];
  int tid = threadIdx.x;
  int lane = tid & 63;
  int wave = tid >> 6;
  int b0 = blockIdx.x * 16;
  int q = lane >> 4;
  int mlo = lane & 15;
  int colw = wave * 48;
  f32x4 acc[3] = {};
  const bf16* arow = yb + ((size_t)(b0 + mlo) * LSEQ + 400) * DI + q * 8;
  for (int k0 = 0; k0 < DI; k0 += 32) {
    short8 a = *(const short8*)(arow + k0);
#pragma unroll
    for (int j = 0; j < 3; ++j) {
      short8 b = *(const short8*)(Wout + (size_t)(colw + j * 16 + mlo) * DI + k0 + q * 8);
      acc[j] = __builtin_amdgcn_mfma_f32_16x16x32_bf16(a, b, acc[j], 0, 0, 0);
    }
  }
#pragma unroll
  for (int j = 0; j < 3; ++j)
#pragma unroll
    for (int i = 0; i < 4; ++i) sCt[q * 4 + i][colw + j * 16 + mlo] = acc[j][i];
  __syncthreads();
  int row = tid >> 4, g = tid & 15;
  int bb = b0 + row;
#pragma unroll
  for (int k = 0; k < 12; ++k) {
    int col = g + 16 * k;
    clsbuf[(size_t)bb * DM + col] =
        sCt[row][col] + resIn[((size_t)bb * LSEQ + 400) * DM + col];
  }
}

// ---------------- final: cls-row norm + head; dtype-flagged output ----------------
__global__ __launch_bounds__(256) void k_final(const float* __restrict__ clsbuf,
                                               const float* __restrict__ fin,
                                               const void* __restrict__ nw_raw,
                                               void* __restrict__ out) {
  const float* normf  = fin + OFF_NORMF;
  const float* head_w = fin + OFF_HEADW;
  const float* head_b = fin + OFF_HEADB;
  __shared__ float clsv[DM];
  __shared__ float partial[4];
  __shared__ float sres;
  int b = blockIdx.x;
  float r = 0.f;
  if (threadIdx.x < DM) r = clsbuf[(size_t)b * DM + threadIdx.x];
  float ss = r * r;
#pragma unroll
  for (int m = 32; m >= 1; m >>= 1) ss += __shfl_xor(ss, m, 64);
  if ((threadIdx.x & 63) == 0) partial[threadIdx.x >> 6] = ss;
  __syncthreads();
  if (threadIdx.x == 0)
    sres = rsqrtf((partial[0] + partial[1] + partial[2] + partial[3]) / (float)DM + EPSF);
  __syncthreads();
  if (threadIdx.x < DM) clsv[threadIdx.x] = r * sres * normf[threadIdx.x];
  __syncthreads();
  int isbf = (((const unsigned short*)nw_raw)[0] == 0x3F80) ? 1 : 0;
  for (int e = threadIdx.x; e < 1000; e += 256) {
    float acc = head_b[e];
    for (int k = 0; k < DM; ++k) acc = fmaf(clsv[k], head_w[e * DM + k], acc);
    if (isbf) ((bf16*)out)[b * 1000 + e] = __float2bfloat16(acc);
    else      ((float*)out)[b * 1000 + e] = acc;
  }
}

extern "C" void kernel_launch(void* const* d_in, const int* in_sizes, int n_in,
                              void* d_out, int out_size, void* d_ws, size_t ws_size,
                              hipStream_t stream) {
  char* base = (char*)d_ws;
  size_t off = 0;
  auto alloc = [&](size_t bytes) { char* p = base + off; off = (off + bytes + 255) & ~(size_t)255; return p; };
  float* fin      = (float*)alloc((size_t)OFF_TOTAL * 4);
  bf16*  wb       = (bf16*)alloc((size_t)WB_TOTAL * 2);
  float* residual = (float*)alloc((size_t)NT * DM * 4);
  bf16*  xb       = (bf16*)alloc((size_t)NT * DI * 2);
  bf16*  zb       = (bf16*)alloc((size_t)NT * DI * 2);
  bf16*  ub       = (bf16*)alloc((size_t)NT * DI * 2);
  float* xdbl     = (float*)alloc((size_t)NT * 44 * 4);
  bf16*  dtb16    = (bf16*)alloc((size_t)NT * DI * 2);
  float* Pq       = (float*)alloc((size_t)2 * PQN * 4);
  float* clsbuf   = (float*)alloc((size_t)B_SZ * DM * 4);
  bf16*  yb       = ub;          // in-place y over u (per-tile read-before-write)

  P18 t;
  for (int i = 0; i < 18; ++i) t.p[i] = d_in[i];
  k_convwb<<<(OFF_TOTAL + WB_TOTAL + 255) / 256, 256, 0, stream>>>(t, fin, wb);

  // embed + rmsnorm + in_proj layer 0
  k_embedin<<<NT / 16, 512, 0, stream>>>(fin, residual, wb + WB_INW, xb, zb);

  for (int layer = 0; layer < 4; ++layer) {
    const float* dtb = fin + OFF_DTB + layer * DI;
    const float* alog = fin + OFF_ALOG + layer * DI * DS;

    // conv+silu -> u ; x_proj MFMA ; dt via MFMA
    k_xdt<<<NT / 16, 512, 0, stream>>>(xb, fin + OFF_CONVW + layer * DI * 4,
                                       fin + OFF_CONVB + layer * DI,
                                       wb + WB_XPJ + layer * 64 * DI, xdbl,
                                       wb + WB_DTW + layer * 384 * 32, dtb, ub, dtb16);

    k_scanA<<<dim3(12, B_SZ, NCH - 1), 512, 0, stream>>>(ub, dtb16, xdbl, alog, Pq);
    k_scanB<<<dim3(12, B_SZ, NCH), 512, 0, stream>>>(zb, ub, dtb16, xdbl, alog,
                                                     fin + OFF_DP + layer * DI, Pq, yb);

    if (layer < 3) {
      k_outin<<<NT / 16, 512, 0, stream>>>(yb, wb + WB_OUT + layer * DM * DI, residual,
                                           fin + OFF_NORMW + (layer + 1) * DM,
                                           wb + WB_INW + (layer + 1) * 768 * DM, xb, zb);
    } else {
      k_lastout<<<2, 256, 0, stream>>>(yb, wb + WB_OUT + 3 * DM * DI, residual, clsbuf);
    }
  }
  k_final<<<B_SZ, 256, 0, stream>>>(clsbuf, fin, d_in[5], d_out);
}